// Round 1
// 888.522 us; speedup vs baseline: 1.0173x; 1.0173x over previous
//
#include <hip/hip_runtime.h>
#include <stdint.h>

// ---------------------------------------------------------------------------
// SigmoidAttentionJoiner on MI355X (gfx950)
// M = N*T*S = 16*512*5 = 40960 rows, J = 512, V = 2000 (padded to 2048)
// All GEMMs: bf16 MFMA 16x16x32, 128x128 tile, BK=32, 256 threads (2x2 waves,
// each wave 64x64 via 4x4 fragment grid) — m97-style structure.
//
// This round:
//  - LayerNorm folded into the Q/KV GEMMs:  LN(x)·Wᵀ = rstd·(x·W′ᵀ) − mu·rstd·rs + b′
//    with W′ = W·diag(g), rs = rowsum(W′), b′ = b + W·beta. Row stats (Σ, Σx²)
//    are accumulated by atomics in the enc/dec GEMM epilogues. LN kernel deleted.
//  - K and V GEMMs merged into one N=1024 GEMM (Wk,Wv adjacent in weight buf).
//  - XCD-chunked blockIdx swizzle (T1) on all GEMMs (all grids nwg%8==0).
// ---------------------------------------------------------------------------

typedef __attribute__((ext_vector_type(8))) __bf16 bf16x8;
typedef __attribute__((ext_vector_type(4))) float float4v;
typedef __attribute__((ext_vector_type(8))) unsigned short ushort8;

static constexpr int M_TOT = 16 * 512 * 5;   // 40960
static constexpr int JDIM  = 512;
static constexpr int VOUT  = 2000;
static constexpr int VPAD  = 2048;

#define DI __device__ __forceinline__

DI float bf2f(unsigned short u) {
    union { unsigned int i; float f; } w; w.i = ((unsigned int)u) << 16; return w.f;
}
DI unsigned short f2bf(float f) {
    union { float f; unsigned int i; } w; w.f = f;
    return (unsigned short)((w.i + 0x8000u) >> 16);   // round-to-nearest (ties away)
}

// async global->LDS, 16B per lane. LDS dest is wave-uniform base + lane*16,
// our chunk indexing is exactly lane-contiguous so this is safe (m104 caveat).
DI void gld_lds16(const void* g, void* l) {
    __builtin_amdgcn_global_load_lds(
        reinterpret_cast<__attribute__((address_space(1))) void*>(
            reinterpret_cast<uintptr_t>(g)),
        reinterpret_cast<__attribute__((address_space(3))) void*>(
            reinterpret_cast<uintptr_t>(l)),
        16, 0, 0);
}

// ---------------------------------------------------------------------------
// GEMM: C[m,n] = sum_k A[m,k] * B[n,k] (+ epilogue)   (B^T layout = (out,in))
// EPI 2: store bf16 tanh(dres + acc + bias), ld = 512
// EPI 3: store fp32 acc + bias, ld = NOUT, mask col < NOUT (grid padded)
// EPI 4: LN-affine: store bf16( rstd*acc + (-mu*rstd)*rs[col] + bias[col] ),
//        row stats read from st_sum/st_ssq (bias arg = b′)
// EPI 6: store bf16(acc + bias); accumulate row Σ / Σx² into st_sum/st_ssq
// A32: A is fp32, converted to bf16 during LDS staging
// ---------------------------------------------------------------------------
template <int EPI, int NOUT, bool A32>
__global__ __launch_bounds__(256) void gemm_bt(
    const void* __restrict__ Ap, const unsigned short* __restrict__ B,
    const float* __restrict__ bias, void* __restrict__ Cp,
    const unsigned short* __restrict__ dres,
    float* __restrict__ st_sum, float* __restrict__ st_ssq,
    const float* __restrict__ rs)
{
    constexpr int K = 512;
    constexpr int BM = 128, BN = 128, BK = 32;
    __shared__ unsigned short As[BM * BK];
    __shared__ unsigned short Bs[BN * BK];

    const int tid  = threadIdx.x;
    const int wave = tid >> 6;
    const int lane = tid & 63;
    const int wm   = wave >> 1;      // 0..1
    const int wn   = wave & 1;       // 0..1
    const int quad = lane >> 4;      // 0..3
    const int l16  = lane & 15;

    // XCD-chunked bijective swizzle (all launch grids have nwg % 8 == 0):
    // HW round-robins linear wg id across 8 XCDs; remap so each XCD owns a
    // contiguous logical range -> A-panels stay within one XCD's L2.
    const int gx      = gridDim.x;
    const int nwg     = gx * gridDim.y;
    const int id      = blockIdx.x + gx * blockIdx.y;
    const int logical = (id & 7) * (nwg >> 3) + (id >> 3);
    const int m0 = (logical / gx) * BM;
    const int n0 = (logical % gx) * BN;

    float4v acc[4][4];
#pragma unroll
    for (int i = 0; i < 4; i++)
#pragma unroll
        for (int j = 0; j < 4; j++)
            acc[i][j] = {0.f, 0.f, 0.f, 0.f};

    const float*          Af = (const float*)Ap;
    const unsigned short* Ab = (const unsigned short*)Ap;

    // staging chunks: 512 chunks of 8 elems per tile; thread covers c and c+256
    const int c0 = tid, c1 = tid + 256;
    const int ar0 = c0 >> 2, ac0 = (c0 & 3) * 8;
    const int ar1 = c1 >> 2, ac1 = (c1 & 3) * 8;

    for (int k0 = 0; k0 < K; k0 += BK) {
        gld_lds16(&B[(size_t)(n0 + ar0) * K + k0 + ac0], &Bs[c0 * 8]);
        gld_lds16(&B[(size_t)(n0 + ar1) * K + k0 + ac1], &Bs[c1 * 8]);
        if constexpr (A32) {
            const float* p0 = &Af[(size_t)(m0 + ar0) * K + k0 + ac0];
            const float* p1 = &Af[(size_t)(m0 + ar1) * K + k0 + ac1];
            float4 f0 = *(const float4*)p0;
            float4 f1 = *(const float4*)(p0 + 4);
            float4 g0 = *(const float4*)p1;
            float4 g1 = *(const float4*)(p1 + 4);
            ushort8 u0, u1;
            u0[0] = f2bf(f0.x); u0[1] = f2bf(f0.y); u0[2] = f2bf(f0.z); u0[3] = f2bf(f0.w);
            u0[4] = f2bf(f1.x); u0[5] = f2bf(f1.y); u0[6] = f2bf(f1.z); u0[7] = f2bf(f1.w);
            u1[0] = f2bf(g0.x); u1[1] = f2bf(g0.y); u1[2] = f2bf(g0.z); u1[3] = f2bf(g0.w);
            u1[4] = f2bf(g1.x); u1[5] = f2bf(g1.y); u1[6] = f2bf(g1.z); u1[7] = f2bf(g1.w);
            *reinterpret_cast<ushort8*>(&As[c0 * 8]) = u0;
            *reinterpret_cast<ushort8*>(&As[c1 * 8]) = u1;
        } else {
            gld_lds16(&Ab[(size_t)(m0 + ar0) * K + k0 + ac0], &As[c0 * 8]);
            gld_lds16(&Ab[(size_t)(m0 + ar1) * K + k0 + ac1], &As[c1 * 8]);
        }
        __syncthreads();

        bf16x8 af[4], bfv[4];
#pragma unroll
        for (int i = 0; i < 4; i++)
            af[i] = *reinterpret_cast<const bf16x8*>(
                &As[(wm * 64 + i * 16 + l16) * BK + quad * 8]);
#pragma unroll
        for (int j = 0; j < 4; j++)
            bfv[j] = *reinterpret_cast<const bf16x8*>(
                &Bs[(wn * 64 + j * 16 + l16) * BK + quad * 8]);
#pragma unroll
        for (int i = 0; i < 4; i++)
#pragma unroll
            for (int j = 0; j < 4; j++)
                acc[i][j] = __builtin_amdgcn_mfma_f32_16x16x32_bf16(
                    af[i], bfv[j], acc[i][j], 0, 0, 0);
        __syncthreads();
    }

    float bias_v[4], rs_v[4];
#pragma unroll
    for (int j = 0; j < 4; j++) {
        int col = n0 + wn * 64 + j * 16 + l16;
        bias_v[j] = (col < NOUT) ? bias[col] : 0.f;
        if constexpr (EPI == 4) rs_v[j] = rs[col];
    }

    if constexpr (EPI == 4) {
        // LN folded: val = rstd*acc + (-mu*rstd)*rs[col] + b'[col]
#pragma unroll
        for (int i = 0; i < 4; i++) {
            int rbase = m0 + wm * 64 + i * 16 + quad * 4;
#pragma unroll
            for (int r = 0; r < 4; r++) {
                int row = rbase + r;
                float s  = st_sum[row];
                float s2 = st_ssq[row];
                float mean = s * (1.f / 512.f);
                float var  = s2 * (1.f / 512.f) - mean * mean;
                float rstd = rsqrtf(var + 1e-5f);
                float crow = -mean * rstd;
#pragma unroll
                for (int j = 0; j < 4; j++) {
                    int col = n0 + wn * 64 + j * 16 + l16;
                    float val = fmaf(rstd, acc[i][j][r],
                                fmaf(crow, rs_v[j], bias_v[j]));
                    ((unsigned short*)Cp)[(size_t)row * NOUT + col] = f2bf(val);
                }
            }
        }
    } else {
#pragma unroll
        for (int i = 0; i < 4; i++) {
            int rbase = m0 + wm * 64 + i * 16 + quad * 4;
#pragma unroll
            for (int j = 0; j < 4; j++) {
                int col = n0 + wn * 64 + j * 16 + l16;
#pragma unroll
                for (int r = 0; r < 4; r++) {
                    float val = acc[i][j][r] + bias_v[j];
                    int row = rbase + r;
                    if constexpr (EPI == 2) {
                        float d = bf2f(dres[(size_t)row * 512 + col]);
                        ((unsigned short*)Cp)[(size_t)row * 512 + col] = f2bf(tanhf(d + val));
                    } else if constexpr (EPI == 3) {
                        if (col < NOUT)
                            ((float*)Cp)[(size_t)row * NOUT + col] = val;
                    } else {  // EPI == 6
                        ((unsigned short*)Cp)[(size_t)row * NOUT + col] = f2bf(val);
                    }
                }
            }
        }
    }

    if constexpr (EPI == 6) {
        // row partial sums over this block's 128 cols -> global atomics.
        // wave covers 64 cols: j(4) x l16(16). Reduce j locally, l16 via shfl.
#pragma unroll
        for (int i = 0; i < 4; i++) {
#pragma unroll
            for (int r = 0; r < 4; r++) {
                float ps = 0.f, ps2 = 0.f;
#pragma unroll
                for (int j = 0; j < 4; j++) {
                    float v = acc[i][j][r] + bias_v[j];
                    ps += v;
                    ps2 = fmaf(v, v, ps2);
                }
#pragma unroll
                for (int m = 1; m < 16; m <<= 1) {
                    ps  += __shfl_xor(ps,  m, 64);
                    ps2 += __shfl_xor(ps2, m, 64);
                }
                if (l16 == 0) {
                    int row = m0 + wm * 64 + i * 16 + quad * 4 + r;
                    atomicAdd(&st_sum[row], ps);
                    atomicAdd(&st_ssq[row], ps2);
                }
            }
        }
    }
}

// ---------------------------------------------------------------------------
// weights fp32 -> bf16 (concatenated buffer; Wout padded to 2048 rows w/ zeros)
// Wq scaled by g_q[col], Wk/Wv scaled by g_kv[col]  (LN gain folded in).
// Also zeroes the 163840-float row-stats region.
// ---------------------------------------------------------------------------
__global__ __launch_bounds__(256) void wconv_kernel(
    const float* __restrict__ We, const float* __restrict__ Wd,
    const float* __restrict__ Wq, const float* __restrict__ Wk,
    const float* __restrict__ Wv, const float* __restrict__ Wo,
    const float* __restrict__ Wout,
    const float* __restrict__ g_q, const float* __restrict__ g_kv,
    unsigned short* __restrict__ WB, float* __restrict__ stz)
{
#pragma unroll
    for (int t = 0; t < 4; t++) {
        int i = blockIdx.x * 1024 + t * 256 + threadIdx.x;   // total 2,621,440 exact
        float v;
        if (i < 1572864) {
            int seg = i >> 18, off = i & 262143;
            const float* src = seg == 0 ? We : seg == 1 ? Wd : seg == 2 ? Wq
                             : seg == 3 ? Wk : seg == 4 ? Wv : Wo;
            v = src[off];
            int j = off & 511;
            if (seg == 2)                 v *= g_q[j];
            else if (seg == 3 || seg == 4) v *= g_kv[j];
        } else {
            int rem = i - 1572864;          // Wout region, 2048x512
            int row = rem >> 9;
            v = (row < VOUT) ? Wout[rem] : 0.f;
        }
        WB[i] = f2bf(v);
    }
    int z = blockIdx.x * 256 + threadIdx.x;   // 0..655359 >= 163840
    if (z < 163840) stz[z] = 0.f;
}

// ---------------------------------------------------------------------------
// LN-fold prep: rs[k] = sum_j W[k,j]*g[j];  b'[k] = b[k] + sum_j W[k,j]*beta[j]
// rows: 0..511 -> Wq (g_q,beta_q,bq); 512..1023 -> Wk; 1024..1535 -> Wv
// (k,v outputs land in rs_kv/b_kv at [0,512) and [512,1024) resp.)
// ---------------------------------------------------------------------------
__global__ __launch_bounds__(256) void lnprep_kernel(
    const float* __restrict__ Wq, const float* __restrict__ Wk,
    const float* __restrict__ Wv,
    const float* __restrict__ g_q, const float* __restrict__ beta_q,
    const float* __restrict__ g_kv, const float* __restrict__ beta_kv,
    const float* __restrict__ bq, const float* __restrict__ bk,
    const float* __restrict__ bv,
    float* __restrict__ rs_q, float* __restrict__ b_q,
    float* __restrict__ rs_kv, float* __restrict__ b_kv)
{
    int idx  = blockIdx.x * 4 + (threadIdx.x >> 6);   // 0..1535
    int lane = threadIdx.x & 63;
    const float *W, *g, *bt, *bb; float *rs_out, *b_out; int r;
    if (idx < 512)       { W = Wq; g = g_q;  bt = beta_q;  bb = bq;
                           rs_out = &rs_q[idx];        b_out = &b_q[idx];        r = idx; }
    else if (idx < 1024) { W = Wk; g = g_kv; bt = beta_kv; bb = bk;
                           rs_out = &rs_kv[idx - 512]; b_out = &b_kv[idx - 512]; r = idx - 512; }
    else                 { W = Wv; g = g_kv; bt = beta_kv; bb = bv;
                           rs_out = &rs_kv[idx - 512]; b_out = &b_kv[idx - 512]; r = idx - 1024; }

    const float* wr = &W[(size_t)r * 512];
    float s = 0.f, sb = 0.f;
    int j0 = lane * 8;
    float4 w0 = *(const float4*)&wr[j0];
    float4 w1 = *(const float4*)&wr[j0 + 4];
    float4 ga = *(const float4*)&g[j0];
    float4 gb = *(const float4*)&g[j0 + 4];
    float4 ba = *(const float4*)&bt[j0];
    float4 bb4 = *(const float4*)&bt[j0 + 4];
    s  += w0.x * ga.x + w0.y * ga.y + w0.z * ga.z + w0.w * ga.w;
    s  += w1.x * gb.x + w1.y * gb.y + w1.z * gb.z + w1.w * gb.w;
    sb += w0.x * ba.x + w0.y * ba.y + w0.z * ba.z + w0.w * ba.w;
    sb += w1.x * bb4.x + w1.y * bb4.y + w1.z * bb4.z + w1.w * bb4.w;
#pragma unroll
    for (int m = 1; m < 64; m <<= 1) {
        s  += __shfl_xor(s,  m, 64);
        sb += __shfl_xor(sb, m, 64);
    }
    if (lane == 0) { *rs_out = s; *b_out = bb[r] + sb; }
}

// ---------------------------------------------------------------------------
// framewise sigmoid attention: one wave per row; head h = lanes [8h, 8h+8)
// kv layout: [row][0..512) = k, [row][512..1024) = v
// ---------------------------------------------------------------------------
__global__ __launch_bounds__(256) void attn_kernel(
    const unsigned short* __restrict__ q, const unsigned short* __restrict__ kv,
    unsigned short* __restrict__ ctx)
{
    int row  = blockIdx.x * 4 + (threadIdx.x >> 6);
    int lane = threadIdx.x & 63;
    size_t qoff = (size_t)row * 512 + lane * 8;
    size_t kvo  = (size_t)row * 1024 + lane * 8;
    ushort8 uq = *reinterpret_cast<const ushort8*>(&q[qoff]);
    ushort8 uk = *reinterpret_cast<const ushort8*>(&kv[kvo]);
    float dot = 0.f;
#pragma unroll
    for (int j = 0; j < 8; j++) dot += bf2f(uq[j]) * bf2f(uk[j]);
    dot += __shfl_xor(dot, 1, 64);
    dot += __shfl_xor(dot, 2, 64);
    dot += __shfl_xor(dot, 4, 64);
    float sg = 1.f / (1.f + __expf(-dot * 0.125f));
    ushort8 uv = *reinterpret_cast<const ushort8*>(&kv[kvo + 512]);
    ushort8 o;
#pragma unroll
    for (int j = 0; j < 8; j++) o[j] = f2bf(sg * bf2f(uv[j]));
    *reinterpret_cast<ushort8*>(&ctx[qoff]) = o;
}

// ---------------------------------------------------------------------------
extern "C" void kernel_launch(void* const* d_in, const int* in_sizes, int n_in,
                              void* d_out, int out_size, void* d_ws, size_t ws_size,
                              hipStream_t stream)
{
    (void)in_sizes; (void)n_in; (void)out_size; (void)ws_size;
    const float* enc_in  = (const float*)d_in[0];
    const float* dec_in  = (const float*)d_in[1];
    const float* We      = (const float*)d_in[2];  const float* be     = (const float*)d_in[3];
    const float* Wd      = (const float*)d_in[4];  const float* bd     = (const float*)d_in[5];
    const float* g_q     = (const float*)d_in[6];  const float* beta_q = (const float*)d_in[7];
    const float* g_kv    = (const float*)d_in[8];  const float* beta_kv= (const float*)d_in[9];
    const float* Wq      = (const float*)d_in[10]; const float* bq     = (const float*)d_in[11];
    const float* Wk      = (const float*)d_in[12]; const float* bk     = (const float*)d_in[13];
    const float* Wv      = (const float*)d_in[14]; const float* bv     = (const float*)d_in[15];
    const float* Wo      = (const float*)d_in[16]; const float* bo     = (const float*)d_in[17];
    const float* Wout    = (const float*)d_in[18]; const float* bout   = (const float*)d_in[19];
    float* out = (float*)d_out;

    // bf16 weight buffer layout (elements)
    unsigned short* WB    = (unsigned short*)d_ws;
    unsigned short* WeB   = WB + 0;
    unsigned short* WdB   = WB + 262144;
    unsigned short* WqB   = WB + 524288;
    unsigned short* WkB   = WB + 786432;   // Wk then Wv contiguous => KV B, N=1024
    unsigned short* WoB   = WB + 1310720;
    unsigned short* WoutB = WB + 1572864;  // 2048 x 512 (zero-padded rows)

    // six aliased M x 512 bf16 slots
    char* sbase = (char*)d_ws + 5242880;
    const size_t SZ = (size_t)M_TOT * 512 * 2;   // 41,943,040 B
    unsigned short* S0 = (unsigned short*)(sbase + 0 * SZ);  // encO
    unsigned short* S1 = (unsigned short*)(sbase + 1 * SZ);  // decO (live to tanh)
    unsigned short* S2 = (unsigned short*)(sbase + 2 * SZ);  // kv (M x 1024, spans S2+S3)
    unsigned short* S3 = (unsigned short*)(sbase + 3 * SZ);  // later: h
    unsigned short* S4 = (unsigned short*)(sbase + 4 * SZ);  // q
    unsigned short* S5 = (unsigned short*)(sbase + 5 * SZ);  // stats/prep, then ctx

    // small fp32 scratch lives at the head of S5 (ctx only written after all
    // consumers of these arrays have run; stream order guarantees safety)
    float* stf  = (float*)(sbase + 5 * SZ);
    float* sumD = stf;             // dec row sums   [40960]
    float* ssqD = stf + 40960;
    float* sumE = stf + 81920;     // enc row sums
    float* ssqE = stf + 122880;
    float* rs_q  = stf + 163840;   // [512]
    float* b_q   = stf + 164352;   // [512]
    float* rs_kv = stf + 164864;   // [1024]
    float* b_kv  = stf + 165888;   // [1024]  (end: 166912 floats = 668 KB << SZ)

    dim3 blk(256);
    dim3 g512(JDIM / 128, M_TOT / 128);     // (4, 320)  nwg=1280
    dim3 g1024(1024 / 128, M_TOT / 128);    // (8, 320)  nwg=2560
    dim3 gout(VPAD / 128, M_TOT / 128);     // (16, 320) nwg=5120

    wconv_kernel<<<2560, blk, 0, stream>>>(We, Wd, Wq, Wk, Wv, Wo, Wout,
                                           g_q, g_kv, WB, stf);
    lnprep_kernel<<<384, blk, 0, stream>>>(Wq, Wk, Wv, g_q, beta_q, g_kv, beta_kv,
                                           bq, bk, bv, rs_q, b_q, rs_kv, b_kv);

    // input projections + row-stat accumulation
    gemm_bt<6, 512, true><<<g512, blk, 0, stream>>>(enc_in, WeB, be, S0, nullptr,
                                                    sumE, ssqE, nullptr);
    gemm_bt<6, 512, true><<<g512, blk, 0, stream>>>(dec_in, WdB, bd, S1, nullptr,
                                                    sumD, ssqD, nullptr);

    // LN-folded projections: q from decO, [k|v] from encO
    gemm_bt<4, 512, false><<<g512, blk, 0, stream>>>(S1, WqB, b_q, S4, nullptr,
                                                     sumD, ssqD, rs_q);
    gemm_bt<4, 1024, false><<<g1024, blk, 0, stream>>>(S0, WkB, b_kv, S2, nullptr,
                                                       sumE, ssqE, rs_kv);

    attn_kernel<<<M_TOT / 4, blk, 0, stream>>>(S4, S2, S5);

    gemm_bt<2, 512, false><<<g512, blk, 0, stream>>>(S5, WoB, bo, S3, S1,
                                                     nullptr, nullptr, nullptr);

    gemm_bt<3, 2000, false><<<gout, blk, 0, stream>>>(S3, WoutB, bout, out, nullptr,
                                                      nullptr, nullptr, nullptr);
}